// Round 1
// 1059.383 us; speedup vs baseline: 1.0426x; 1.0426x over previous
//
#include <hip/hip_runtime.h>
#include <stdint.h>

#define NB    4
#define TQ    256
#define TS    257
#define TD    65
#define NPIX  16640        /* TQ*TD */
#define NPADQ 264          /* padded s per q */
#define NPAD  67584        /* 256*264 */
#define COUT  512
#define HID   256

typedef __attribute__((ext_vector_type(8))) short bf16x8;
typedef __attribute__((ext_vector_type(4))) float f32x4;

// ---------------- bf16 helpers ----------------
__device__ __forceinline__ float bf2f(unsigned short u) {
    union { unsigned int i; float f; } v; v.i = ((unsigned int)u) << 16; return v.f;
}
__device__ __forceinline__ unsigned short f2bf(float x) {
    union { float f; unsigned int i; } v; v.f = x;
    unsigned int r = v.i + 0x7fffu + ((v.i >> 16) & 1u);
    return (unsigned short)(r >> 16);
}

__device__ __forceinline__ float2 gn_params(const float* st, int bg, float invcnt) {
    float mu  = st[bg * 2] * invcnt;
    float var = st[bg * 2 + 1] * invcnt - mu * mu;
    float2 r; r.x = mu; r.y = rsqrtf(var + 1e-5f); return r;
}

// ---------------- weight cast fp32 -> bf16 ----------------
__global__ void wprep_kernel(const float* __restrict__ wq, const float* __restrict__ wsc,
                             const float* __restrict__ wagg, unsigned short* __restrict__ wb) {
    int i = blockIdx.x * 256 + threadIdx.x;   // grid 1152 -> 294912
    float v;
    if (i < 98304) v = wq[i];
    else if (i < 163840) v = wsc[i - 98304];
    else v = wagg[i - 163840];
    wb[i] = f2bf(v);
}

// ---------------- mask: additive bias table [b][272] (0 or -1e9) ----------------
// s=0 (cls) always active; s in [1,256] gated by gathered mask; s in [257,271] padded off.
__global__ void mask_kernel(const int* __restrict__ sm, float* __restrict__ bias) {
    int b = blockIdx.x; int t = threadIdx.x;   // 320 threads
    if (t >= 272) return;
    float v;
    if (t == 0) v = 0.0f;
    else if (t <= 256) {
        int s = t - 1; int i = s >> 4, j = s & 15;
        v = (sm[(size_t)b * 65536 + i * 17 * 256 + j * 17] != 0) ? 0.0f : -1e9f;
    } else v = -1e9f;
    bias[b * 272 + t] = v;
}

// ---------------- fused transpose + pool: corr -> corrT bf16 [n'][128], corrpT bf16 [n][128] ----
// grid (256 q, 2 chalf, 4 b), 256 threads
__global__ __launch_bounds__(256) void tpool_kernel(
    const float* __restrict__ corr,
    unsigned short* __restrict__ corrT,    // [b][NPAD][128]
    unsigned short* __restrict__ corrpT)   // [b][NPIX][128]
{
    int q = blockIdx.x, ch = blockIdx.y, b = blockIdx.z;
    int t = threadIdx.x;
    __shared__ unsigned short sT[264 * 66];

    // load 64 channels x 257 s, coalesced over s; write [s][c] bf16
    {
        int laneT = t & 63; int crow = t >> 6;
        for (int c = crow; c < 64; c += 4) {
            const float* src = corr + (((size_t)b * 128 + ch * 64 + c) * 256 + q) * 257;
            for (int s = laneT; s < 257; s += 64) sT[s * 66 + c] = f2bf(src[s]);
        }
    }
    // zero pad rows 257..263
    for (int idx = t; idx < 7 * 66; idx += 256) {
        int s = 257 + idx / 66, c = idx % 66;
        sT[s * 66 + c] = 0;
    }
    __syncthreads();

    // corrT out: 264 rows x 32 uints (this chalf)
    {
        unsigned int* dst = (unsigned int*)corrT;
        size_t base = (size_t)b * (NPAD * 64) + (size_t)q * (264 * 64) + ch * 32;
        for (int idx = t; idx < 264 * 32; idx += 256) {
            int s = idx >> 5, cu = idx & 31;
            unsigned int v = (unsigned int)sT[s * 66 + 2 * cu] |
                             ((unsigned int)sT[s * 66 + 2 * cu + 1] << 16);
            dst[base + (size_t)s * 64 + cu] = v;
        }
    }
    // pooled out: 65 d x 32 uints
    {
        unsigned int* dst = (unsigned int*)corrpT;
        size_t base = (size_t)b * (NPIX * 64) + (size_t)q * (65 * 64) + ch * 32;
        for (int idx = t; idx < 65 * 32; idx += 256) {
            int d = idx >> 5, cu = idx & 31;
            float x0, x1;
            if (d == 0) {
                x0 = bf2f(sT[0 * 66 + 2 * cu]); x1 = bf2f(sT[0 * 66 + 2 * cu + 1]);
            } else {
                int dd = d - 1; int i = dd >> 3, j = dd & 7;
                int s = 1 + i * 32 + j * 2;
                int c0 = 2 * cu, c1 = 2 * cu + 1;
                x0 = 0.25f * (bf2f(sT[s*66+c0]) + bf2f(sT[(s+1)*66+c0]) +
                              bf2f(sT[(s+16)*66+c0]) + bf2f(sT[(s+17)*66+c0]));
                x1 = 0.25f * (bf2f(sT[s*66+c1]) + bf2f(sT[(s+1)*66+c1]) +
                              bf2f(sT[(s+16)*66+c1]) + bf2f(sT[(s+17)*66+c1]));
            }
            unsigned int v = (unsigned int)f2bf(x0) | ((unsigned int)f2bf(x1) << 16);
            dst[base + (size_t)d * 64 + cu] = v;
        }
    }
}

// ---------------- unified MFMA GEMM ----------------
// X bf16 [b][Nn][KT] k-contig; Wb bf16 [M][KT].
// MODE 0 (Q):  out Y16[b][n][256] bf16, +bias, mfma(W,X) -> regs = 4 consecutive m
// MODE 1 (KV): m<256 -> kbuf [(b,g,q)][s][32e] scattered b16; m>=256 -> vbuf [b][mv][NPAD] uint2
// MODE 2 (SC): out Yf fp32 [b][512][NPIX]
// MODE 3 (AGG): like SC but gn1+relu transform on X during staging
template<int MODE, int KT>
__global__ __launch_bounds__(256) void mgemm_kernel(
    const unsigned short* __restrict__ X,
    const unsigned short* __restrict__ Wb,
    int Nn,
    float* __restrict__ Yf,
    unsigned short* __restrict__ Y16,
    unsigned short* __restrict__ kb,
    unsigned short* __restrict__ vb,
    const float* __restrict__ bias,
    const float* __restrict__ st, const float* __restrict__ gw, const float* __restrict__ gb,
    float invcnt)
{
    int b  = blockIdx.z;
    int n0 = blockIdx.x * 128;
    int m0 = blockIdx.y * 128;
    int t = threadIdx.x;
    int w = t >> 6, lane = t & 63;
    int lm = lane & 15, lg = lane >> 4;
    int wn = (w & 1) * 64, wm = (w >> 1) * 64;

    __shared__ __align__(16) unsigned short sX[16384];
    __shared__ __align__(16) unsigned short sW[16384];

    f32x4 acc[4][4];
    #pragma unroll
    for (int i = 0; i < 4; i++)
        #pragma unroll
        for (int j = 0; j < 4; j++) { acc[i][j][0]=0.f; acc[i][j][1]=0.f; acc[i][j][2]=0.f; acc[i][j][3]=0.f; }

    for (int kc = 0; kc < KT / 128; kc++) {
        // stage: 2048 uint4 each, direct copy (swizzled k-groups)
        for (int i = t; i < 2048; i += 256) {
            int r_ = i >> 4, kq = i & 15;
            uint4 xv = *(const uint4*)&X[((size_t)b * Nn + n0 + r_) * KT + kc * 128 + (kq << 3)];
            if (MODE == 3) {
                union { uint4 v; unsigned short us[8]; } u; u.v = xv;
                int c0 = kc * 128 + (kq << 3);
                float2 p = gn_params(st, b * 4 + (c0 >> 6), invcnt);
                #pragma unroll
                for (int jj = 0; jj < 8; jj++) {
                    int cc = c0 + jj;
                    float v = bf2f(u.us[jj]);
                    v = fmaxf((v - p.x) * p.y * gw[cc] + gb[cc], 0.0f);
                    u.us[jj] = f2bf(v);
                }
                xv = u.v;
            }
            *(uint4*)&sX[r_ * 128 + ((kq ^ (r_ & 15)) << 3)] = xv;
            uint4 wv = *(const uint4*)&Wb[((size_t)(m0 + r_)) * KT + kc * 128 + (kq << 3)];
            *(uint4*)&sW[r_ * 128 + ((kq ^ (r_ & 15)) << 3)] = wv;
        }
        __syncthreads();
        #pragma unroll
        for (int kk = 0; kk < 4; kk++) {
            int kg = (kk << 2) | lg;
            bf16x8 af[4], bw[4];
            #pragma unroll
            for (int ii = 0; ii < 4; ii++)
                af[ii] = *(const bf16x8*)&sX[(wn + ii * 16 + lm) * 128 + ((kg ^ lm) << 3)];
            #pragma unroll
            for (int jj = 0; jj < 4; jj++)
                bw[jj] = *(const bf16x8*)&sW[(wm + jj * 16 + lm) * 128 + ((kg ^ lm) << 3)];
            #pragma unroll
            for (int ii = 0; ii < 4; ii++)
                #pragma unroll
                for (int jj = 0; jj < 4; jj++) {
                    if (MODE == 0)
                        acc[ii][jj] = __builtin_amdgcn_mfma_f32_16x16x32_bf16(bw[jj], af[ii], acc[ii][jj], 0,0,0);
                    else
                        acc[ii][jj] = __builtin_amdgcn_mfma_f32_16x16x32_bf16(af[ii], bw[jj], acc[ii][jj], 0,0,0);
                }
        }
        __syncthreads();
    }

    if (MODE == 0) {
        // regs = 4 consecutive m (row = lg*4+r), col n = lm
        #pragma unroll
        for (int ii = 0; ii < 4; ii++) {
            int n = n0 + wn + ii * 16 + lm;
            #pragma unroll
            for (int jj = 0; jj < 4; jj++) {
                int mb = m0 + wm + jj * 16 + lg * 4;
                union { unsigned short us[4]; uint2 v; } pk;
                #pragma unroll
                for (int r = 0; r < 4; r++) pk.us[r] = f2bf(acc[ii][jj][r] + bias[mb + r]);
                *(uint2*)&Y16[((size_t)b * NPIX + n) * 256 + mb] = pk.v;
            }
        }
    } else if (MODE == 1) {
        if (m0 < 256) {   // K half: scattered b16 into [(b,g,q)][s][32]
            #pragma unroll
            for (int ii = 0; ii < 4; ii++) {
                #pragma unroll
                for (int r = 0; r < 4; r++) {
                    unsigned int np = (unsigned int)(n0 + wn + ii * 16 + lg * 4 + r);
                    unsigned int qq = np / 264u;
                    unsigned int s  = np - qq * 264u;
                    #pragma unroll
                    for (int jj = 0; jj < 4; jj++) {
                        int m = m0 + wm + jj * 16 + lm;
                        int gch = m >> 5, e = m & 31;
                        kb[(((size_t)(b * 8 + gch) * 256 + qq) * 264 + s) * 32 + e] =
                            f2bf(acc[ii][jj][r] + bias[m]);
                    }
                }
            }
        } else {          // V half: uint2 into [b][mv][NPAD]
            #pragma unroll
            for (int ii = 0; ii < 4; ii++) {
                int nb = n0 + wn + ii * 16 + lg * 4;
                #pragma unroll
                for (int jj = 0; jj < 4; jj++) {
                    int m = m0 + wm + jj * 16 + lm;
                    int mv = m - 256;
                    union { unsigned short us[4]; uint2 v; } pk;
                    #pragma unroll
                    for (int r = 0; r < 4; r++) pk.us[r] = f2bf(acc[ii][jj][r] + bias[m]);
                    *(uint2*)&vb[((size_t)b * 256 + mv) * NPAD + nb] = pk.v;
                }
            }
        }
    } else {
        // fp32 [b][512][NPIX], regs = 4 consecutive n
        #pragma unroll
        for (int ii = 0; ii < 4; ii++) {
            int nb = n0 + wn + ii * 16 + lg * 4;
            #pragma unroll
            for (int jj = 0; jj < 4; jj++) {
                int m = m0 + wm + jj * 16 + lm;
                *(f32x4*)&Yf[((size_t)b * COUT + m) * NPIX + nb] = acc[ii][jj];
            }
        }
    }
}

// ---------------- MFMA attention, zero barriers, batched-ILP + S^T orientation ----------
// grid (8, 256, 4) = (g, q, b); 320 threads = 5 waves, wave w owns d in [16w,16w+16)
// QK^T computed as mfma(K,Q) so each lane owns ONE d row (d = 16w + lm) with s spread
// over 17 tiles x 4 regs (s = 16tt + 4lg + r): softmax reduce = 2 shfls; P->LDS becomes
// 17 packed b64 writes. K (17) and V (18) fragments are batch-loaded into register
// arrays so all global latencies overlap (previous version at 52 VGPRs serialized them).
__global__ __launch_bounds__(320, 3) void attn_kernel(
    const unsigned short* __restrict__ kb,   // [(b,g,q)][264 s][32 e]
    const unsigned short* __restrict__ vb,   // [b][256 ch][NPAD]
    const unsigned short* __restrict__ qpT,  // [b][NPIX][256]
    const float* __restrict__ bias272,       // [b][272] additive mask bias
    unsigned short* __restrict__ attT)       // [b][NPIX][256]
{
    int g = blockIdx.x, q = blockIdx.y, b = blockIdx.z;
    int t = threadIdx.x;
    int w = t >> 6, lane = t & 63;
    int lm = lane & 15, lg = lane >> 4;

    __shared__ __align__(16) unsigned short sP[23040];   // 5 waves x 16 x 288
    unsigned short* sPw = sP + w * 4608;

    // Q frag (B operand: lane holds Q[d=16w+lm][e=g*32+lg*8+j]); clamp + zero d>=65
    int d = w * 16 + lm;
    int dc = d < 64 ? d : 64;
    bf16x8 qa = *(const bf16x8*)&qpT[((size_t)b * NPIX + q * 65 + dc) * 256 + g * 32 + lg * 8];
    if (d >= TD) { bf16x8 z = {}; qa = z; }

    // ---- batched K loads: all 17 fragments in flight ----
    size_t kb0 = ((size_t)(b * 8 + g) * 256 + q) * (264 * 32);
    const unsigned short* kp = kb + kb0 + (size_t)lm * 32 + lg * 8;
    bf16x8 kf[17];
    #pragma unroll
    for (int tt = 0; tt < 17; tt++)
        kf[tt] = *(const bf16x8*)&kp[tt * 512];

    // ---- QK^T transposed: c[tt] holds S^T[s_local=lg*4+r][d=lm] ----
    f32x4 zero4 = {0.f, 0.f, 0.f, 0.f};
    f32x4 c[17];
    #pragma unroll
    for (int tt = 0; tt < 17; tt++)
        c[tt] = __builtin_amdgcn_mfma_f32_16x16x32_bf16(kf[tt], qa, zero4, 0, 0, 0);

    // ---- batched V loads (independent of softmax; latency hides under VALU) ----
    size_t vb0 = ((size_t)b * 256 + g * 32) * NPAD + (size_t)q * 264;
    const unsigned short* vp = vb + vb0 + (size_t)lm * NPAD + lg * 8;
    bf16x8 vf0[9], vf1[9];
    #pragma unroll
    for (int kk = 0; kk < 9; kk++) {
        vf0[kk] = *(const bf16x8*)&vp[kk * 32];
        vf1[kk] = *(const bf16x8*)&vp[16 * NPAD + kk * 32];
    }

    // ---- additive mask bias: one aligned float4 per tile ----
    const float* bp = bias272 + b * 272 + lg * 4;
    #pragma unroll
    for (int tt = 0; tt < 17; tt++) {
        f32x4 bf = *(const f32x4*)&bp[tt * 16];
        c[tt][0] += bf[0]; c[tt][1] += bf[1]; c[tt][2] += bf[2]; c[tt][3] += bf[3];
    }

    // ---- softmax: lane-local row d=lm, reduce over lg via 2 shfls ----
    f32x4 mv = c[0];
    #pragma unroll
    for (int tt = 1; tt < 17; tt++) {
        mv[0] = fmaxf(mv[0], c[tt][0]); mv[1] = fmaxf(mv[1], c[tt][1]);
        mv[2] = fmaxf(mv[2], c[tt][2]); mv[3] = fmaxf(mv[3], c[tt][3]);
    }
    float mx = fmaxf(fmaxf(mv[0], mv[1]), fmaxf(mv[2], mv[3]));
    mx = fmaxf(mx, __shfl_xor(mx, 16));
    mx = fmaxf(mx, __shfl_xor(mx, 32));
    float sm = 0.f;
    #pragma unroll
    for (int tt = 0; tt < 17; tt++) {
        #pragma unroll
        for (int r = 0; r < 4; r++) { float e_ = __expf(c[tt][r] - mx); c[tt][r] = e_; sm += e_; }
    }
    sm += __shfl_xor(sm, 16);
    sm += __shfl_xor(sm, 32);
    float inv = 1.0f / sm;

    // ---- P -> wave-private swizzled LDS [d][s]: one b64 write per tile ----
    #pragma unroll
    for (int tt = 0; tt < 17; tt++) {
        union { unsigned short us[4]; uint2 v; } pk;
        #pragma unroll
        for (int r = 0; r < 4; r++) pk.us[r] = f2bf(c[tt][r] * inv);
        int sg = tt * 2 + (lg >> 1);                       // 16B slot = s>>3
        int off = lm * 288 + ((sg ^ (lm & 3)) << 3) + (lg & 1) * 4;
        *(uint2*)&sPw[off] = pk.v;
    }
    // zero logical slots 34,35 (s in [272,288)) of own row
    if (lg < 2) {
        int sg = 34 + lg;
        uint4 z4 = {0u, 0u, 0u, 0u};
        *(uint4*)&sPw[lm * 288 + ((sg ^ (lm & 3)) << 3)] = z4;
    }

    // ---- PV: P from wave-private LDS, V from registers (no barrier needed) ----
    f32x4 o0 = zero4, o1 = zero4;
    #pragma unroll
    for (int kk = 0; kk < 9; kk++) {
        int kg = kk * 4 + lg;
        bf16x8 pa = *(const bf16x8*)&sPw[lm * 288 + ((kg ^ (lm & 3)) << 3)];
        o0 = __builtin_amdgcn_mfma_f32_16x16x32_bf16(pa, vf0[kk], o0, 0, 0, 0);
        o1 = __builtin_amdgcn_mfma_f32_16x16x32_bf16(pa, vf1[kk], o1, 0, 0, 0);
    }
    // store attT bf16 [n][256]
    #pragma unroll
    for (int r = 0; r < 4; r++) {
        int dd = w * 16 + lg * 4 + r;
        if (dd < TD) {
            size_t nn = (size_t)b * NPIX + q * 65 + dd;
            attT[nn * 256 + g * 32 + lm]      = f2bf(o0[r]);
            attT[nn * 256 + g * 32 + 16 + lm] = f2bf(o1[r]);
        }
    }
}

// ---------------- stats over bf16 attT [b][NPIX][256], groups of 64 channels ----------------
__global__ void stats1_kernel(const unsigned short* __restrict__ attT, float* __restrict__ st) {
    int b = blockIdx.y;
    int t = threadIdx.x;
    int e8 = t & 31, g = e8 >> 3;
    int lane = t & 63;
    float s = 0.f, ss = 0.f;
    for (int r = blockIdx.x * 8 + (t >> 5); r < NPIX; r += gridDim.x * 8) {
        union { uint4 v; unsigned short us[8]; } u;
        u.v = *(const uint4*)&attT[((size_t)b * NPIX + r) * 256 + e8 * 8];
        #pragma unroll
        for (int j = 0; j < 8; j++) { float x = bf2f(u.us[j]); s += x; ss += x * x; }
    }
    s += __shfl_down(s, 32); ss += __shfl_down(ss, 32);
    s += __shfl_down(s, 4);  ss += __shfl_down(ss, 4);
    s += __shfl_down(s, 2);  ss += __shfl_down(ss, 2);
    s += __shfl_down(s, 1);  ss += __shfl_down(ss, 1);
    if (lane < 32 && (lane & 7) == 0) {
        atomicAdd(&st[(b * 4 + g) * 2],     s);
        atomicAdd(&st[(b * 4 + g) * 2 + 1], ss);
    }
}

// ---------------- stats over fp32 [b][C][NPIX], contiguous (b,g) spans ----------------
__global__ void stats_kernel(const float* __restrict__ x, float* __restrict__ st, int Cg) {
    size_t len = (size_t)Cg * NPIX;
    size_t base = (size_t)blockIdx.y * len;
    const float4* x4 = reinterpret_cast<const float4*>(x + base);
    size_t len4 = len >> 2;
    float s = 0.f, ss = 0.f;
    for (size_t i = (size_t)blockIdx.x * blockDim.x + threadIdx.x; i < len4;
         i += (size_t)gridDim.x * blockDim.x) {
        float4 v = x4[i];
        s  += v.x + v.y + v.z + v.w;
        ss += v.x * v.x + v.y * v.y + v.z * v.z + v.w * v.w;
    }
    #pragma unroll
    for (int o = 32; o > 0; o >>= 1) { s += __shfl_down(s, o, 64); ss += __shfl_down(ss, o, 64); }
    __shared__ float red[4][2];
    int wid = threadIdx.x >> 6, lane = threadIdx.x & 63;
    if (lane == 0) { red[wid][0] = s; red[wid][1] = ss; }
    __syncthreads();
    if (threadIdx.x == 0) {
        float S  = red[0][0] + red[1][0] + red[2][0] + red[3][0];
        float SS = red[0][1] + red[1][1] + red[2][1] + red[3][1];
        atomicAdd(&st[blockIdx.y * 2],     S);
        atomicAdd(&st[blockIdx.y * 2 + 1], SS);
    }
}

// ---------------- z = relu(gn2(agg)) + relu(gn_sc(scr)), in place on agg ----------------
__global__ void z_kernel(float* __restrict__ out, const float* __restrict__ scr,
                         const float* __restrict__ st2, const float* __restrict__ stsc,
                         const float* __restrict__ g2w, const float* __restrict__ g2b,
                         const float* __restrict__ gsw, const float* __restrict__ gsb)
{
    const float invcnt = 1.0f / (128.0f * NPIX);
    size_t total4 = (size_t)NB * COUT * (NPIX / 4);
    float4* o4 = reinterpret_cast<float4*>(out);
    const float4* s4 = reinterpret_cast<const float4*>(scr);
    for (size_t i = (size_t)blockIdx.x * blockDim.x + threadIdx.x; i < total4;
         i += (size_t)gridDim.x * blockDim.x) {
        size_t flat = i * 4;
        int c = (int)((flat / NPIX) % COUT);
        int b = (int)(flat / ((size_t)COUT * NPIX));
        int bg = b * 4 + (c >> 7);
        float2 p2 = gn_params(st2,  bg, invcnt);
        float2 ps = gn_params(stsc, bg, invcnt);
        float w2 = g2w[c] * p2.y, b2 = g2b[c] - p2.x * p2.y * g2w[c];
        float wsc = gsw[c] * ps.y, bsc = gsb[c] - ps.x * ps.y * gsw[c];
        float4 a = o4[i], r = s4[i], z;
        z.x = fmaxf(a.x * w2 + b2, 0.f) + fmaxf(r.x * wsc + bsc, 0.f);
        z.y = fmaxf(a.y * w2 + b2, 0.f) + fmaxf(r.y * wsc + bsc, 0.f);
        z.z = fmaxf(a.z * w2 + b2, 0.f) + fmaxf(r.z * wsc + bsc, 0.f);
        z.w = fmaxf(a.w * w2 + b2, 0.f) + fmaxf(r.w * wsc + bsc, 0.f);
        o4[i] = z;
    }
}

// ---------------- final gn_out, in place ----------------
__global__ void norm_kernel(float* __restrict__ out, const float* __restrict__ st3,
                            const float* __restrict__ gw, const float* __restrict__ gb)
{
    const float invcnt = 1.0f / (128.0f * NPIX);
    size_t total4 = (size_t)NB * COUT * (NPIX / 4);
    float4* o4 = reinterpret_cast<float4*>(out);
    for (size_t i = (size_t)blockIdx.x * blockDim.x + threadIdx.x; i < total4;
         i += (size_t)gridDim.x * blockDim.x) {
        size_t flat = i * 4;
        int c = (int)((flat / NPIX) % COUT);
        int b = (int)(flat / ((size_t)COUT * NPIX));
        int bg = b * 4 + (c >> 7);
        float2 p = gn_params(st3, bg, invcnt);
        float w_ = gw[c] * p.y, b_ = gb[c] - p.x * p.y * gw[c];
        float4 a = o4[i], z;
        z.x = a.x * w_ + b_; z.y = a.y * w_ + b_; z.z = a.z * w_ + b_; z.w = a.w * w_ + b_;
        o4[i] = z;
    }
}

extern "C" void kernel_launch(void* const* d_in, const int* in_sizes, int n_in,
                              void* d_out, int out_size, void* d_ws, size_t ws_size,
                              hipStream_t stream) {
    (void)in_sizes; (void)n_in; (void)out_size; (void)ws_size;
    const float* corr     = (const float*)d_in[0];
    const int*   smask    = (const int*)  d_in[1];
    const float* W_sc     = (const float*)d_in[2];
    const float* gn_sc_w  = (const float*)d_in[3];
    const float* gn_sc_b  = (const float*)d_in[4];
    const float* W_qkv    = (const float*)d_in[5];
    const float* b_qkv    = (const float*)d_in[6];
    const float* gn1_w    = (const float*)d_in[7];
    const float* gn1_b    = (const float*)d_in[8];
    const float* W_agg    = (const float*)d_in[9];
    const float* gn2_w    = (const float*)d_in[10];
    const float* gn2_b    = (const float*)d_in[11];
    const float* gn_out_w = (const float*)d_in[12];
    const float* gn_out_b = (const float*)d_in[13];
    float* out = (float*)d_out;

    unsigned short* ws = (unsigned short*)d_ws;
    unsigned short* corrT  = ws;                           // 34,603,008 sh
    unsigned short* kbuf   = corrT  + (size_t)34603008;    // 69,206,016 sh
    unsigned short* vbuf   = kbuf   + (size_t)69206016;    // 69,206,016 sh
    unsigned short* corrpT = vbuf   + (size_t)69206016;    //  8,519,680 sh
    unsigned short* qpT    = corrpT + (size_t)8519680;     // 17,039,360 sh
    unsigned short* attT   = qpT    + (size_t)17039360;    // 17,039,360 sh
    unsigned short* wbuf   = attT   + (size_t)17039360;    //    294,912 sh
    float* bias  = (float*)(wbuf + (size_t)294912);        // 1,088 f  ([b][272])
    float* stats = bias + 1088;                            // 128 f
    float* scr   = (float*)d_ws;   // aliases corrT+kbuf head (both dead by then)
    float* st_sc = stats, *st1 = stats + 32, *st2 = stats + 64, *st3 = stats + 96;

    const float inv1 = 1.0f / (64.0f * (float)NPIX);

    hipMemsetAsync(stats, 0, 128 * sizeof(float), stream);
    wprep_kernel<<<dim3(1152), dim3(256), 0, stream>>>(W_qkv, W_sc, W_agg, wbuf);
    mask_kernel<<<dim3(NB), dim3(320), 0, stream>>>(smask, bias);
    tpool_kernel<<<dim3(TQ, 2, NB), dim3(256), 0, stream>>>(corr, corrT, corrpT);
    // Q projection: qpT[b][n][256] = Wq x corrpT + bq
    mgemm_kernel<0,128><<<dim3(130, 2, NB), dim3(256), 0, stream>>>(
        corrpT, wbuf, NPIX, nullptr, qpT, nullptr, nullptr, b_qkv,
        nullptr, nullptr, nullptr, 0.f);
    // K/V projection from corrT
    mgemm_kernel<1,128><<<dim3(528, 4, NB), dim3(256), 0, stream>>>(
        corrT, wbuf + 32768, NPAD, nullptr, nullptr, kbuf, vbuf, b_qkv + 256,
        nullptr, nullptr, nullptr, 0.f);
    attn_kernel<<<dim3(8, TQ, NB), dim3(320), 0, stream>>>(kbuf, vbuf, qpT, bias, attT);
    stats1_kernel<<<dim3(208, NB), dim3(256), 0, stream>>>(attT, st1);
    // agg conv with fused gn1+relu on input: out = W_agg x relu(gn1(attT))
    mgemm_kernel<3,256><<<dim3(130, 4, NB), dim3(256), 0, stream>>>(
        attT, wbuf + 163840, NPIX, out, nullptr, nullptr, nullptr, nullptr,
        st1, gn1_w, gn1_b, inv1);
    stats_kernel<<<dim3(64, 16), dim3(256), 0, stream>>>(out, st2, 128);
    // residual conv: scr = W_sc x corrpT (scr aliases dead corrT/kbuf head)
    mgemm_kernel<2,128><<<dim3(130, 4, NB), dim3(256), 0, stream>>>(
        corrpT, wbuf + 98304, NPIX, scr, nullptr, nullptr, nullptr, nullptr,
        nullptr, nullptr, nullptr, 0.f);
    stats_kernel<<<dim3(64, 16), dim3(256), 0, stream>>>(scr, st_sc, 128);
    z_kernel<<<dim3(4096), dim3(256), 0, stream>>>(out, scr, st2, st_sc, gn2_w, gn2_b, gn_sc_w, gn_sc_b);
    stats_kernel<<<dim3(64, 16), dim3(256), 0, stream>>>(out, st3, 128);
    norm_kernel<<<dim3(4096), dim3(256), 0, stream>>>(out, st3, gn_out_w, gn_out_b);
}

// Round 2
// 982.366 us; speedup vs baseline: 1.1243x; 1.0784x over previous
//
#include <hip/hip_runtime.h>
#include <stdint.h>

#define NB    4
#define TQ    256
#define TS    257
#define TD    65
#define NPIX  16640        /* TQ*TD */
#define NPADQ 264          /* padded s per q */
#define NPAD  67584        /* 256*264 */
#define COUT  512
#define HID   256

typedef __attribute__((ext_vector_type(8))) short bf16x8;
typedef __attribute__((ext_vector_type(4))) float f32x4;

// ---------------- bf16 helpers ----------------
__device__ __forceinline__ float bf2f(unsigned short u) {
    union { unsigned int i; float f; } v; v.i = ((unsigned int)u) << 16; return v.f;
}
__device__ __forceinline__ unsigned short f2bf(float x) {
    union { float f; unsigned int i; } v; v.f = x;
    unsigned int r = v.i + 0x7fffu + ((v.i >> 16) & 1u);
    return (unsigned short)(r >> 16);
}

__device__ __forceinline__ float2 gn_params(const float* st, int bg, float invcnt) {
    float mu  = st[bg * 2] * invcnt;
    float var = st[bg * 2 + 1] * invcnt - mu * mu;
    float2 r; r.x = mu; r.y = rsqrtf(var + 1e-5f); return r;
}

// async global->LDS, 16B per lane; LDS dest = uniform base + lane*16
__device__ __forceinline__ void gld_lds16(const void* g, void* l) {
    __builtin_amdgcn_global_load_lds(
        (const __attribute__((address_space(1))) unsigned int*)(size_t)g,
        (__attribute__((address_space(3))) unsigned int*)(unsigned int)(size_t)l,
        16, 0, 0);
}

// ---------------- weight cast fp32 -> bf16 ----------------
__global__ void wprep_kernel(const float* __restrict__ wq, const float* __restrict__ wsc,
                             const float* __restrict__ wagg, unsigned short* __restrict__ wb) {
    int i = blockIdx.x * 256 + threadIdx.x;   // grid 1152 -> 294912
    float v;
    if (i < 98304) v = wq[i];
    else if (i < 163840) v = wsc[i - 98304];
    else v = wagg[i - 163840];
    wb[i] = f2bf(v);
}

// ---------------- mask: additive bias table [b][272] (0 or -1e9) ----------------
__global__ void mask_kernel(const int* __restrict__ sm, float* __restrict__ bias) {
    int b = blockIdx.x; int t = threadIdx.x;   // 320 threads
    if (t >= 272) return;
    float v;
    if (t == 0) v = 0.0f;
    else if (t <= 256) {
        int s = t - 1; int i = s >> 4, j = s & 15;
        v = (sm[(size_t)b * 65536 + i * 17 * 256 + j * 17] != 0) ? 0.0f : -1e9f;
    } else v = -1e9f;
    bias[b * 272 + t] = v;
}

// ---------------- fused transpose + pool ----------------
__global__ __launch_bounds__(256) void tpool_kernel(
    const float* __restrict__ corr,
    unsigned short* __restrict__ corrT,    // [b][NPAD][128]
    unsigned short* __restrict__ corrpT)   // [b][NPIX][128]
{
    int q = blockIdx.x, ch = blockIdx.y, b = blockIdx.z;
    int t = threadIdx.x;
    __shared__ unsigned short sT[264 * 66];

    {
        int laneT = t & 63; int crow = t >> 6;
        for (int c = crow; c < 64; c += 4) {
            const float* src = corr + (((size_t)b * 128 + ch * 64 + c) * 256 + q) * 257;
            for (int s = laneT; s < 257; s += 64) sT[s * 66 + c] = f2bf(src[s]);
        }
    }
    for (int idx = t; idx < 7 * 66; idx += 256) {
        int s = 257 + idx / 66, c = idx % 66;
        sT[s * 66 + c] = 0;
    }
    __syncthreads();

    {
        unsigned int* dst = (unsigned int*)corrT;
        size_t base = (size_t)b * (NPAD * 64) + (size_t)q * (264 * 64) + ch * 32;
        for (int idx = t; idx < 264 * 32; idx += 256) {
            int s = idx >> 5, cu = idx & 31;
            unsigned int v = (unsigned int)sT[s * 66 + 2 * cu] |
                             ((unsigned int)sT[s * 66 + 2 * cu + 1] << 16);
            dst[base + (size_t)s * 64 + cu] = v;
        }
    }
    {
        unsigned int* dst = (unsigned int*)corrpT;
        size_t base = (size_t)b * (NPIX * 64) + (size_t)q * (65 * 64) + ch * 32;
        for (int idx = t; idx < 65 * 32; idx += 256) {
            int d = idx >> 5, cu = idx & 31;
            float x0, x1;
            if (d == 0) {
                x0 = bf2f(sT[0 * 66 + 2 * cu]); x1 = bf2f(sT[0 * 66 + 2 * cu + 1]);
            } else {
                int dd = d - 1; int i = dd >> 3, j = dd & 7;
                int s = 1 + i * 32 + j * 2;
                int c0 = 2 * cu, c1 = 2 * cu + 1;
                x0 = 0.25f * (bf2f(sT[s*66+c0]) + bf2f(sT[(s+1)*66+c0]) +
                              bf2f(sT[(s+16)*66+c0]) + bf2f(sT[(s+17)*66+c0]));
                x1 = 0.25f * (bf2f(sT[s*66+c1]) + bf2f(sT[(s+1)*66+c1]) +
                              bf2f(sT[(s+16)*66+c1]) + bf2f(sT[(s+17)*66+c1]));
            }
            unsigned int v = (unsigned int)f2bf(x0) | ((unsigned int)f2bf(x1) << 16);
            dst[base + (size_t)d * 64 + cu] = v;
        }
    }
}

// ---------------- unified MFMA GEMM (unchanged) ----------------
template<int MODE, int KT>
__global__ __launch_bounds__(256) void mgemm_kernel(
    const unsigned short* __restrict__ X,
    const unsigned short* __restrict__ Wb,
    int Nn,
    float* __restrict__ Yf,
    unsigned short* __restrict__ Y16,
    unsigned short* __restrict__ kb,
    unsigned short* __restrict__ vb,
    const float* __restrict__ bias,
    const float* __restrict__ st, const float* __restrict__ gw, const float* __restrict__ gb,
    float invcnt)
{
    int b  = blockIdx.z;
    int n0 = blockIdx.x * 128;
    int m0 = blockIdx.y * 128;
    int t = threadIdx.x;
    int w = t >> 6, lane = t & 63;
    int lm = lane & 15, lg = lane >> 4;
    int wn = (w & 1) * 64, wm = (w >> 1) * 64;

    __shared__ __align__(16) unsigned short sX[16384];
    __shared__ __align__(16) unsigned short sW[16384];

    f32x4 acc[4][4];
    #pragma unroll
    for (int i = 0; i < 4; i++)
        #pragma unroll
        for (int j = 0; j < 4; j++) { acc[i][j][0]=0.f; acc[i][j][1]=0.f; acc[i][j][2]=0.f; acc[i][j][3]=0.f; }

    for (int kc = 0; kc < KT / 128; kc++) {
        for (int i = t; i < 2048; i += 256) {
            int r_ = i >> 4, kq = i & 15;
            uint4 xv = *(const uint4*)&X[((size_t)b * Nn + n0 + r_) * KT + kc * 128 + (kq << 3)];
            if (MODE == 3) {
                union { uint4 v; unsigned short us[8]; } u; u.v = xv;
                int c0 = kc * 128 + (kq << 3);
                float2 p = gn_params(st, b * 4 + (c0 >> 6), invcnt);
                #pragma unroll
                for (int jj = 0; jj < 8; jj++) {
                    int cc = c0 + jj;
                    float v = bf2f(u.us[jj]);
                    v = fmaxf((v - p.x) * p.y * gw[cc] + gb[cc], 0.0f);
                    u.us[jj] = f2bf(v);
                }
                xv = u.v;
            }
            *(uint4*)&sX[r_ * 128 + ((kq ^ (r_ & 15)) << 3)] = xv;
            uint4 wv = *(const uint4*)&Wb[((size_t)(m0 + r_)) * KT + kc * 128 + (kq << 3)];
            *(uint4*)&sW[r_ * 128 + ((kq ^ (r_ & 15)) << 3)] = wv;
        }
        __syncthreads();
        #pragma unroll
        for (int kk = 0; kk < 4; kk++) {
            int kg = (kk << 2) | lg;
            bf16x8 af[4], bw[4];
            #pragma unroll
            for (int ii = 0; ii < 4; ii++)
                af[ii] = *(const bf16x8*)&sX[(wn + ii * 16 + lm) * 128 + ((kg ^ lm) << 3)];
            #pragma unroll
            for (int jj = 0; jj < 4; jj++)
                bw[jj] = *(const bf16x8*)&sW[(wm + jj * 16 + lm) * 128 + ((kg ^ lm) << 3)];
            #pragma unroll
            for (int ii = 0; ii < 4; ii++)
                #pragma unroll
                for (int jj = 0; jj < 4; jj++) {
                    if (MODE == 0)
                        acc[ii][jj] = __builtin_amdgcn_mfma_f32_16x16x32_bf16(bw[jj], af[ii], acc[ii][jj], 0,0,0);
                    else
                        acc[ii][jj] = __builtin_amdgcn_mfma_f32_16x16x32_bf16(af[ii], bw[jj], acc[ii][jj], 0,0,0);
                }
        }
        __syncthreads();
    }

    if (MODE == 0) {
        #pragma unroll
        for (int ii = 0; ii < 4; ii++) {
            int n = n0 + wn + ii * 16 + lm;
            #pragma unroll
            for (int jj = 0; jj < 4; jj++) {
                int mb = m0 + wm + jj * 16 + lg * 4;
                union { unsigned short us[4]; uint2 v; } pk;
                #pragma unroll
                for (int r = 0; r < 4; r++) pk.us[r] = f2bf(acc[ii][jj][r] + bias[mb + r]);
                *(uint2*)&Y16[((size_t)b * NPIX + n) * 256 + mb] = pk.v;
            }
        }
    } else if (MODE == 1) {
        if (m0 < 256) {
            #pragma unroll
            for (int ii = 0; ii < 4; ii++) {
                #pragma unroll
                for (int r = 0; r < 4; r++) {
                    unsigned int np = (unsigned int)(n0 + wn + ii * 16 + lg * 4 + r);
                    unsigned int qq = np / 264u;
                    unsigned int s  = np - qq * 264u;
                    #pragma unroll
                    for (int jj = 0; jj < 4; jj++) {
                        int m = m0 + wm + jj * 16 + lm;
                        int gch = m >> 5, e = m & 31;
                        kb[(((size_t)(b * 8 + gch) * 256 + qq) * 264 + s) * 32 + e] =
                            f2bf(acc[ii][jj][r] + bias[m]);
                    }
                }
            }
        } else {
            #pragma unroll
            for (int ii = 0; ii < 4; ii++) {
                int nb = n0 + wn + ii * 16 + lg * 4;
                #pragma unroll
                for (int jj = 0; jj < 4; jj++) {
                    int m = m0 + wm + jj * 16 + lm;
                    int mv = m - 256;
                    union { unsigned short us[4]; uint2 v; } pk;
                    #pragma unroll
                    for (int r = 0; r < 4; r++) pk.us[r] = f2bf(acc[ii][jj][r] + bias[m]);
                    *(uint2*)&vb[((size_t)b * 256 + mv) * NPAD + nb] = pk.v;
                }
            }
        }
    } else {
        #pragma unroll
        for (int ii = 0; ii < 4; ii++) {
            int nb = n0 + wn + ii * 16 + lg * 4;
            #pragma unroll
            for (int jj = 0; jj < 4; jj++) {
                int m = m0 + wm + jj * 16 + lm;
                *(f32x4*)&Yf[((size_t)b * COUT + m) * NPIX + nb] = acc[ii][jj];
            }
        }
    }
}

// ---------------- MFMA attention: DMA-staged K/V in LDS + in-register P transpose ----
// grid (8, 256, 4) = (g, q, b); 320 threads = 5 waves, wave w owns d in [16w,16w+16)
// LDS: K at [0,17408) bytes = 68 macro-rows(256B) = [272 s][32 e] swizzled;
//      V at [17408,35840) = 72 macro-rows = [9 kk][32 ch][4 lg][16B] swizzled.
// Swizzle: 16B-slot sl within each 256B macro-row stored at sl ^ (mr&15); DMA keeps
// LDS linear and pre-applies the involution on the per-lane GLOBAL source address.
__global__ __launch_bounds__(320, 3) void attn_kernel(
    const unsigned short* __restrict__ kb,   // [(b,g,q)][264 s][32 e]
    const unsigned short* __restrict__ vb,   // [b][256 ch][NPAD]
    const unsigned short* __restrict__ qpT,  // [b][NPIX][256]
    const unsigned short* __restrict__ zpad, // >=16B of guaranteed zeros (corrT pad row)
    const float* __restrict__ bias272,       // [b][272] additive mask bias
    unsigned short* __restrict__ attT)       // [b][NPIX][256]
{
    int g = blockIdx.x, q = blockIdx.y, b = blockIdx.z;
    int t = threadIdx.x;
    int w = t >> 6, lane = t & 63;
    int lm = lane & 15, lg = lane >> 4;

    __shared__ __align__(16) unsigned short sbuf[17920];   // 35840 B: K then V
    const int VB = 8704;                                    // V base in shorts

    // Q frag (B operand: lane holds Q[d=16w+lm][e=g*32+lg*8+j]); clamp + zero d>=65
    int d = w * 16 + lm;
    int dc = d < 64 ? d : 64;
    bf16x8 qa = *(const bf16x8*)&qpT[((size_t)b * NPIX + q * 65 + dc) * 256 + g * 32 + lg * 8];
    if (d >= TD) { bf16x8 z = {}; qa = z; }

    // ---- async staging: 35 chunks of 1KB (17 K + 18 V), 7 per wave ----
    size_t kb0 = ((size_t)(b * 8 + g) * 256 + q) * (264 * 32);   // shorts
    size_t vrow0 = (size_t)b * 256 + g * 32;
    for (int cc = w; cc < 35; cc += 5) {
        unsigned o = cc * 1024 + lane * 16;       // LDS byte offset
        const unsigned short* src;
        if (cc < 17) {                            // K region
            unsigned mr = o >> 8, sl = (o >> 4) & 15;
            unsigned lam = (o & ~0xF0u) | ((sl ^ (mr & 15)) << 4);
            src = (lam < 16896u) ? (kb + kb0 + (lam >> 1)) : zpad;
        } else {                                  // V region
            unsigned ov = o - 17408u;
            unsigned mr = ov >> 8, sl = (ov >> 4) & 15;
            unsigned lam = (ov & ~0xF0u) | ((sl ^ (mr & 15)) << 4);
            unsigned kk = lam >> 11, ch = (lam >> 6) & 31;
            unsigned s = kk * 32 + ((lam >> 4) & 3) * 8;
            src = (s < 264u) ? (vb + ((vrow0 + ch) * NPAD + (size_t)q * 264 + s)) : zpad;
        }
        gld_lds16(src, &sbuf[cc * 512]);
    }
    asm volatile("s_waitcnt vmcnt(0)" ::: "memory");
    __syncthreads();

    // ---- QK^T from LDS: c[tt] holds S^T[s=16tt+4lg+r][d=lm] ----
    f32x4 zero4 = {0.f, 0.f, 0.f, 0.f};
    f32x4 c[17];
    int sl0 = ((lm & 3) << 2) | lg;
    #pragma unroll
    for (int tt = 0; tt < 17; tt++) {
        int mr = tt * 4 + (lm >> 2);
        bf16x8 kf = *(const bf16x8*)&sbuf[mr * 128 + ((sl0 ^ (mr & 15)) << 3)];
        c[tt] = __builtin_amdgcn_mfma_f32_16x16x32_bf16(kf, qa, zero4, 0, 0, 0);
    }

    // ---- additive mask bias: one aligned float4 per tile ----
    const float* bp = bias272 + b * 272 + lg * 4;
    #pragma unroll
    for (int tt = 0; tt < 17; tt++) {
        f32x4 bf = *(const f32x4*)&bp[tt * 16];
        c[tt][0] += bf[0]; c[tt][1] += bf[1]; c[tt][2] += bf[2]; c[tt][3] += bf[3];
    }

    // ---- softmax: row d=lm lane-local over regs; reduce across lg via 2 shfls ----
    f32x4 mv = c[0];
    #pragma unroll
    for (int tt = 1; tt < 17; tt++) {
        mv[0] = fmaxf(mv[0], c[tt][0]); mv[1] = fmaxf(mv[1], c[tt][1]);
        mv[2] = fmaxf(mv[2], c[tt][2]); mv[3] = fmaxf(mv[3], c[tt][3]);
    }
    float mx = fmaxf(fmaxf(mv[0], mv[1]), fmaxf(mv[2], mv[3]));
    mx = fmaxf(mx, __shfl_xor(mx, 16));
    mx = fmaxf(mx, __shfl_xor(mx, 32));
    float sm = 0.f;
    #pragma unroll
    for (int tt = 0; tt < 17; tt++) {
        #pragma unroll
        for (int r = 0; r < 4; r++) { float e_ = __expf(c[tt][r] - mx); c[tt][r] = e_; sm += e_; }
    }
    sm += __shfl_xor(sm, 16);
    sm += __shfl_xor(sm, 32);
    float inv = 1.0f / sm;   // uniform across lg for fixed lm; applied at epilogue

    // ---- pack P (unnormalized) to bf16 pairs ----
    unsigned plo[17], phi[17];
    #pragma unroll
    for (int tt = 0; tt < 17; tt++) {
        asm("v_cvt_pk_bf16_f32 %0, %1, %2" : "=v"(plo[tt]) : "v"(c[tt][0]), "v"(c[tt][1]));
        asm("v_cvt_pk_bf16_f32 %0, %1, %2" : "=v"(phi[tt]) : "v"(c[tt][2]), "v"(c[tt][3]));
    }

    // ---- PV: in-register transpose (permlane32_swap + shfl_xor16) + V from LDS ----
    bool lgEven = (lane & 16) == 0;
    f32x4 o0 = zero4, o1 = zero4;
    #pragma unroll
    for (int kk = 0; kk < 9; kk++) {
        unsigned A = plo[2 * kk];
        unsigned C = phi[2 * kk];
        unsigned B = (2 * kk + 1 < 17) ? plo[2 * kk + 1] : 0u;
        unsigned D = (2 * kk + 1 < 17) ? phi[2 * kk + 1] : 0u;
        // A=[lo_low|lo2_low] B=[lo_high|lo2_high]; C,D same for hi pair
        asm("v_permlane32_swap_b32 %0, %1" : "+v"(A), "+v"(B));
        asm("v_permlane32_swap_b32 %0, %1" : "+v"(C), "+v"(D));
        unsigned Ax = __shfl_xor(A, 16), Bx = __shfl_xor(B, 16);
        unsigned Cx = __shfl_xor(C, 16), Dx = __shfl_xor(D, 16);
        union { unsigned u[4]; bf16x8 v; } pa;
        pa.u[0] = lgEven ? A  : Bx;
        pa.u[1] = lgEven ? C  : Dx;
        pa.u[2] = lgEven ? Ax : B;
        pa.u[3] = lgEven ? Cx : D;
        int mr0 = kk * 8 + (lm >> 2), mr1 = mr0 + 4;
        bf16x8 v0 = *(const bf16x8*)&sbuf[VB + mr0 * 128 + ((sl0 ^ (mr0 & 15)) << 3)];
        bf16x8 v1 = *(const bf16x8*)&sbuf[VB + mr1 * 128 + ((sl0 ^ (mr1 & 15)) << 3)];
        o0 = __builtin_amdgcn_mfma_f32_16x16x32_bf16(pa.v, v0, o0, 0, 0, 0);
        o1 = __builtin_amdgcn_mfma_f32_16x16x32_bf16(pa.v, v1, o1, 0, 0, 0);
    }
    // ---- epilogue: apply 1/sum (gather per-row inv) and store ----
    float invr[4];
    #pragma unroll
    for (int r = 0; r < 4; r++) invr[r] = __shfl(inv, lg * 4 + r);
    #pragma unroll
    for (int r = 0; r < 4; r++) {
        int dd = w * 16 + lg * 4 + r;
        if (dd < TD) {
            size_t nn = (size_t)b * NPIX + q * 65 + dd;
            attT[nn * 256 + g * 32 + lm]      = f2bf(o0[r] * invr[r]);
            attT[nn * 256 + g * 32 + 16 + lm] = f2bf(o1[r] * invr[r]);
        }
    }
}

// ---------------- stats over bf16 attT ----------------
__global__ void stats1_kernel(const unsigned short* __restrict__ attT, float* __restrict__ st) {
    int b = blockIdx.y;
    int t = threadIdx.x;
    int e8 = t & 31, g = e8 >> 3;
    int lane = t & 63;
    float s = 0.f, ss = 0.f;
    for (int r = blockIdx.x * 8 + (t >> 5); r < NPIX; r += gridDim.x * 8) {
        union { uint4 v; unsigned short us[8]; } u;
        u.v = *(const uint4*)&attT[((size_t)b * NPIX + r) * 256 + e8 * 8];
        #pragma unroll
        for (int j = 0; j < 8; j++) { float x = bf2f(u.us[j]); s += x; ss += x * x; }
    }
    s += __shfl_down(s, 32); ss += __shfl_down(ss, 32);
    s += __shfl_down(s, 4);  ss += __shfl_down(ss, 4);
    s += __shfl_down(s, 2);  ss += __shfl_down(ss, 2);
    s += __shfl_down(s, 1);  ss += __shfl_down(ss, 1);
    if (lane < 32 && (lane & 7) == 0) {
        atomicAdd(&st[(b * 4 + g) * 2],     s);
        atomicAdd(&st[(b * 4 + g) * 2 + 1], ss);
    }
}

// ---------------- stats over fp32 [b][C][NPIX] ----------------
__global__ void stats_kernel(const float* __restrict__ x, float* __restrict__ st, int Cg) {
    size_t len = (size_t)Cg * NPIX;
    size_t base = (size_t)blockIdx.y * len;
    const float4* x4 = reinterpret_cast<const float4*>(x + base);
    size_t len4 = len >> 2;
    float s = 0.f, ss = 0.f;
    for (size_t i = (size_t)blockIdx.x * blockDim.x + threadIdx.x; i < len4;
         i += (size_t)gridDim.x * blockDim.x) {
        float4 v = x4[i];
        s  += v.x + v.y + v.z + v.w;
        ss += v.x * v.x + v.y * v.y + v.z * v.z + v.w * v.w;
    }
    #pragma unroll
    for (int o = 32; o > 0; o >>= 1) { s += __shfl_down(s, o, 64); ss += __shfl_down(ss, o, 64); }
    __shared__ float red[4][2];
    int wid = threadIdx.x >> 6, lane = threadIdx.x & 63;
    if (lane == 0) { red[wid][0] = s; red[wid][1] = ss; }
    __syncthreads();
    if (threadIdx.x == 0) {
        float S  = red[0][0] + red[1][0] + red[2][0] + red[3][0];
        float SS = red[0][1] + red[1][1] + red[2][1] + red[3][1];
        atomicAdd(&st[blockIdx.y * 2],     S);
        atomicAdd(&st[blockIdx.y * 2 + 1], SS);
    }
}

// ---------------- z = relu(gn2(agg)) + relu(gn_sc(scr)) ----------------
__global__ void z_kernel(float* __restrict__ out, const float* __restrict__ scr,
                         const float* __restrict__ st2, const float* __restrict__ stsc,
                         const float* __restrict__ g2w, const float* __restrict__ g2b,
                         const float* __restrict__ gsw, const float* __restrict__ gsb)
{
    const float invcnt = 1.0f / (128.0f * NPIX);
    size_t total4 = (size_t)NB * COUT * (NPIX / 4);
    float4* o4 = reinterpret_cast<float4*>(out);
    const float4* s4 = reinterpret_cast<const float4*>(scr);
    for (size_t i = (size_t)blockIdx.x * blockDim.x + threadIdx.x; i < total4;
         i += (size_t)gridDim.x * blockDim.x) {
        size_t flat = i * 4;
        int c = (int)((flat / NPIX) % COUT);
        int b = (int)(flat / ((size_t)COUT * NPIX));
        int bg = b * 4 + (c >> 7);
        float2 p2 = gn_params(st2,  bg, invcnt);
        float2 ps = gn_params(stsc, bg, invcnt);
        float w2 = g2w[c] * p2.y, b2 = g2b[c] - p2.x * p2.y * g2w[c];
        float wsc = gsw[c] * ps.y, bsc = gsb[c] - ps.x * ps.y * gsw[c];
        float4 a = o4[i], r = s4[i], z;
        z.x = fmaxf(a.x * w2 + b2, 0.f) + fmaxf(r.x * wsc + bsc, 0.f);
        z.y = fmaxf(a.y * w2 + b2, 0.f) + fmaxf(r.y * wsc + bsc, 0.f);
        z.z = fmaxf(a.z * w2 + b2, 0.f) + fmaxf(r.z * wsc + bsc, 0.f);
        z.w = fmaxf(a.w * w2 + b2, 0.f) + fmaxf(r.w * wsc + bsc, 0.f);
        o4[i] = z;
    }
}

// ---------------- final gn_out ----------------
__global__ void norm_kernel(float* __restrict__ out, const float* __restrict__ st3,
                            const float* __restrict__ gw, const float* __restrict__ gb)
{
    const float invcnt = 1.0f / (128.0f * NPIX);
    size_t total4 = (size_t)NB * COUT * (NPIX / 4);
    float4* o4 = reinterpret_cast<float4*>(out);
    for (size_t i = (size_t)blockIdx.x * blockDim.x + threadIdx.x; i < total4;
         i += (size_t)gridDim.x * blockDim.x) {
        size_t flat = i * 4;
        int c = (int)((flat / NPIX) % COUT);
        int b = (int)(flat / ((size_t)COUT * NPIX));
        int bg = b * 4 + (c >> 7);
        float2 p = gn_params(st3, bg, invcnt);
        float w_ = gw[c] * p.y, b_ = gb[c] - p.x * p.y * gw[c];
        float4 a = o4[i], z;
        z.x = a.x * w_ + b_; z.y = a.y * w_ + b_; z.z = a.z * w_ + b_; z.w = a.w * w_ + b_;
        o4[i] = z;
    }
}

extern "C" void kernel_launch(void* const* d_in, const int* in_sizes, int n_in,
                              void* d_out, int out_size, void* d_ws, size_t ws_size,
                              hipStream_t stream) {
    (void)in_sizes; (void)n_in; (void)out_size; (void)ws_size;
    const float* corr     = (const float*)d_in[0];
    const int*   smask    = (const int*)  d_in[1];
    const float* W_sc     = (const float*)d_in[2];
    const float* gn_sc_w  = (const float*)d_in[3];
    const float* gn_sc_b  = (const float*)d_in[4];
    const float* W_qkv    = (const float*)d_in[5];
    const float* b_qkv    = (const float*)d_in[6];
    const float* gn1_w    = (const float*)d_in[7];
    const float* gn1_b    = (const float*)d_in[8];
    const float* W_agg    = (const float*)d_in[9];
    const float* gn2_w    = (const float*)d_in[10];
    const float* gn2_b    = (const float*)d_in[11];
    const float* gn_out_w = (const float*)d_in[12];
    const float* gn_out_b = (const float*)d_in[13];
    float* out = (float*)d_out;

    unsigned short* ws = (unsigned short*)d_ws;
    unsigned short* corrT  = ws;                           // 34,603,008 sh
    unsigned short* kbuf   = corrT  + (size_t)34603008;    // 69,206,016 sh
    unsigned short* vbuf   = kbuf   + (size_t)69206016;    // 69,206,016 sh
    unsigned short* corrpT = vbuf   + (size_t)69206016;    //  8,519,680 sh
    unsigned short* qpT    = corrpT + (size_t)8519680;     // 17,039,360 sh
    unsigned short* attT   = qpT    + (size_t)17039360;    // 17,039,360 sh
    unsigned short* wbuf   = attT   + (size_t)17039360;    //    294,912 sh
    float* bias  = (float*)(wbuf + (size_t)294912);        // 1,088 f  ([b][272])
    float* stats = bias + 1088;                            // 128 f
    float* scr   = (float*)d_ws;   // aliases corrT+kbuf head (both dead by then)
    float* st_sc = stats, *st1 = stats + 32, *st2 = stats + 64, *st3 = stats + 96;

    const float inv1 = 1.0f / (64.0f * (float)NPIX);

    hipMemsetAsync(stats, 0, 128 * sizeof(float), stream);
    wprep_kernel<<<dim3(1152), dim3(256), 0, stream>>>(W_qkv, W_sc, W_agg, wbuf);
    mask_kernel<<<dim3(NB), dim3(320), 0, stream>>>(smask, bias);
    tpool_kernel<<<dim3(TQ, 2, NB), dim3(256), 0, stream>>>(corr, corrT, corrpT);
    // Q projection: qpT[b][n][256] = Wq x corrpT + bq
    mgemm_kernel<0,128><<<dim3(130, 2, NB), dim3(256), 0, stream>>>(
        corrpT, wbuf, NPIX, nullptr, qpT, nullptr, nullptr, b_qkv,
        nullptr, nullptr, nullptr, 0.f);
    // K/V projection from corrT
    mgemm_kernel<1,128><<<dim3(528, 4, NB), dim3(256), 0, stream>>>(
        corrT, wbuf + 32768, NPAD, nullptr, nullptr, kbuf, vbuf, b_qkv + 256,
        nullptr, nullptr, nullptr, 0.f);
    // zero source = corrT pad rows (s=257..263 of b=0,q=0, zeroed by tpool)
    attn_kernel<<<dim3(8, TQ, NB), dim3(320), 0, stream>>>(
        kbuf, vbuf, qpT, corrT + 32896, bias, attT);
    stats1_kernel<<<dim3(208, NB), dim3(256), 0, stream>>>(attT, st1);
    // agg conv with fused gn1+relu on input
    mgemm_kernel<3,256><<<dim3(130, 4, NB), dim3(256), 0, stream>>>(
        attT, wbuf + 163840, NPIX, out, nullptr, nullptr, nullptr, nullptr,
        st1, gn1_w, gn1_b, inv1);
    stats_kernel<<<dim3(64, 16), dim3(256), 0, stream>>>(out, st2, 128);
    // residual conv: scr = W_sc x corrpT
    mgemm_kernel<2,128><<<dim3(130, 4, NB), dim3(256), 0, stream>>>(
        corrpT, wbuf + 98304, NPIX, scr, nullptr, nullptr, nullptr, nullptr,
        nullptr, nullptr, nullptr, 0.f);
    stats_kernel<<<dim3(64, 16), dim3(256), 0, stream>>>(scr, st_sc, 128);
    z_kernel<<<dim3(4096), dim3(256), 0, stream>>>(out, scr, st2, st_sc, gn2_w, gn2_b, gn_sc_w, gn_sc_b);
    stats_kernel<<<dim3(64, 16), dim3(256), 0, stream>>>(out, st3, 128);
    norm_kernel<<<dim3(4096), dim3(256), 0, stream>>>(out, st3, gn_out_w, gn_out_b);
}

// Round 3
// 970.732 us; speedup vs baseline: 1.1378x; 1.0120x over previous
//
#include <hip/hip_runtime.h>
#include <stdint.h>

#define NB    4
#define TQ    256
#define TS    257
#define TD    65
#define NPIX  16640        /* TQ*TD */
#define NPADQ 264          /* padded s per q */
#define NPAD  67584        /* 256*264 */
#define COUT  512
#define HID   256

typedef __attribute__((ext_vector_type(8))) short bf16x8;
typedef __attribute__((ext_vector_type(4))) float f32x4;

// ---------------- bf16 helpers ----------------
__device__ __forceinline__ float bf2f(unsigned short u) {
    union { unsigned int i; float f; } v; v.i = ((unsigned int)u) << 16; return v.f;
}
__device__ __forceinline__ unsigned short f2bf(float x) {
    union { float f; unsigned int i; } v; v.f = x;
    unsigned int r = v.i + 0x7fffu + ((v.i >> 16) & 1u);
    return (unsigned short)(r >> 16);
}

__device__ __forceinline__ float2 gn_params(const float* st, int bg, float invcnt) {
    float mu  = st[bg * 2] * invcnt;
    float var = st[bg * 2 + 1] * invcnt - mu * mu;
    float2 r; r.x = mu; r.y = rsqrtf(var + 1e-5f); return r;
}

// ---------------- weight cast fp32 -> bf16 ----------------
__global__ void wprep_kernel(const float* __restrict__ wq, const float* __restrict__ wsc,
                             const float* __restrict__ wagg, unsigned short* __restrict__ wb) {
    int i = blockIdx.x * 256 + threadIdx.x;   // grid 1152 -> 294912
    float v;
    if (i < 98304) v = wq[i];
    else if (i < 163840) v = wsc[i - 98304];
    else v = wagg[i - 163840];
    wb[i] = f2bf(v);
}

// ---------------- mask: additive bias table [b][272] (0 or -1e9) ----------------
__global__ void mask_kernel(const int* __restrict__ sm, float* __restrict__ bias) {
    int b = blockIdx.x; int t = threadIdx.x;   // 320 threads
    if (t >= 272) return;
    float v;
    if (t == 0) v = 0.0f;
    else if (t <= 256) {
        int s = t - 1; int i = s >> 4, j = s & 15;
        v = (sm[(size_t)b * 65536 + i * 17 * 256 + j * 17] != 0) ? 0.0f : -1e9f;
    } else v = -1e9f;
    bias[b * 272 + t] = v;
}

// ---------------- fused transpose + pool ----------------
__global__ __launch_bounds__(256) void tpool_kernel(
    const float* __restrict__ corr,
    unsigned short* __restrict__ corrT,    // [b][NPAD][128]
    unsigned short* __restrict__ corrpT)   // [b][NPIX][128]
{
    int q = blockIdx.x, ch = blockIdx.y, b = blockIdx.z;
    int t = threadIdx.x;
    __shared__ unsigned short sT[264 * 66];

    {
        int laneT = t & 63; int crow = t >> 6;
        for (int c = crow; c < 64; c += 4) {
            const float* src = corr + (((size_t)b * 128 + ch * 64 + c) * 256 + q) * 257;
            for (int s = laneT; s < 257; s += 64) sT[s * 66 + c] = f2bf(src[s]);
        }
    }
    for (int idx = t; idx < 7 * 66; idx += 256) {
        int s = 257 + idx / 66, c = idx % 66;
        sT[s * 66 + c] = 0;
    }
    __syncthreads();

    {
        unsigned int* dst = (unsigned int*)corrT;
        size_t base = (size_t)b * (NPAD * 64) + (size_t)q * (264 * 64) + ch * 32;
        for (int idx = t; idx < 264 * 32; idx += 256) {
            int s = idx >> 5, cu = idx & 31;
            unsigned int v = (unsigned int)sT[s * 66 + 2 * cu] |
                             ((unsigned int)sT[s * 66 + 2 * cu + 1] << 16);
            dst[base + (size_t)s * 64 + cu] = v;
        }
    }
    {
        unsigned int* dst = (unsigned int*)corrpT;
        size_t base = (size_t)b * (NPIX * 64) + (size_t)q * (65 * 64) + ch * 32;
        for (int idx = t; idx < 65 * 32; idx += 256) {
            int d = idx >> 5, cu = idx & 31;
            float x0, x1;
            if (d == 0) {
                x0 = bf2f(sT[0 * 66 + 2 * cu]); x1 = bf2f(sT[0 * 66 + 2 * cu + 1]);
            } else {
                int dd = d - 1; int i = dd >> 3, j = dd & 7;
                int s = 1 + i * 32 + j * 2;
                int c0 = 2 * cu, c1 = 2 * cu + 1;
                x0 = 0.25f * (bf2f(sT[s*66+c0]) + bf2f(sT[(s+1)*66+c0]) +
                              bf2f(sT[(s+16)*66+c0]) + bf2f(sT[(s+17)*66+c0]));
                x1 = 0.25f * (bf2f(sT[s*66+c1]) + bf2f(sT[(s+1)*66+c1]) +
                              bf2f(sT[(s+16)*66+c1]) + bf2f(sT[(s+17)*66+c1]));
            }
            unsigned int v = (unsigned int)f2bf(x0) | ((unsigned int)f2bf(x1) << 16);
            dst[base + (size_t)d * 64 + cu] = v;
        }
    }
}

// ---------------- unified MFMA GEMM (modes 0,2,3 used) ----------------
template<int MODE, int KT>
__global__ __launch_bounds__(256) void mgemm_kernel(
    const unsigned short* __restrict__ X,
    const unsigned short* __restrict__ Wb,
    int Nn,
    float* __restrict__ Yf,
    unsigned short* __restrict__ Y16,
    const float* __restrict__ bias,
    const float* __restrict__ st, const float* __restrict__ gw, const float* __restrict__ gb,
    float invcnt)
{
    int b  = blockIdx.z;
    int n0 = blockIdx.x * 128;
    int m0 = blockIdx.y * 128;
    int t = threadIdx.x;
    int w = t >> 6, lane = t & 63;
    int lm = lane & 15, lg = lane >> 4;
    int wn = (w & 1) * 64, wm = (w >> 1) * 64;

    __shared__ __align__(16) unsigned short sX[16384];
    __shared__ __align__(16) unsigned short sW[16384];

    f32x4 acc[4][4];
    #pragma unroll
    for (int i = 0; i < 4; i++)
        #pragma unroll
        for (int j = 0; j < 4; j++) { acc[i][j][0]=0.f; acc[i][j][1]=0.f; acc[i][j][2]=0.f; acc[i][j][3]=0.f; }

    for (int kc = 0; kc < KT / 128; kc++) {
        for (int i = t; i < 2048; i += 256) {
            int r_ = i >> 4, kq = i & 15;
            uint4 xv = *(const uint4*)&X[((size_t)b * Nn + n0 + r_) * KT + kc * 128 + (kq << 3)];
            if (MODE == 3) {
                union { uint4 v; unsigned short us[8]; } u; u.v = xv;
                int c0 = kc * 128 + (kq << 3);
                float2 p = gn_params(st, b * 4 + (c0 >> 6), invcnt);
                #pragma unroll
                for (int jj = 0; jj < 8; jj++) {
                    int cc = c0 + jj;
                    float v = bf2f(u.us[jj]);
                    v = fmaxf((v - p.x) * p.y * gw[cc] + gb[cc], 0.0f);
                    u.us[jj] = f2bf(v);
                }
                xv = u.v;
            }
            *(uint4*)&sX[r_ * 128 + ((kq ^ (r_ & 15)) << 3)] = xv;
            uint4 wv = *(const uint4*)&Wb[((size_t)(m0 + r_)) * KT + kc * 128 + (kq << 3)];
            *(uint4*)&sW[r_ * 128 + ((kq ^ (r_ & 15)) << 3)] = wv;
        }
        __syncthreads();
        #pragma unroll
        for (int kk = 0; kk < 4; kk++) {
            int kg = (kk << 2) | lg;
            bf16x8 af[4], bw[4];
            #pragma unroll
            for (int ii = 0; ii < 4; ii++)
                af[ii] = *(const bf16x8*)&sX[(wn + ii * 16 + lm) * 128 + ((kg ^ lm) << 3)];
            #pragma unroll
            for (int jj = 0; jj < 4; jj++)
                bw[jj] = *(const bf16x8*)&sW[(wm + jj * 16 + lm) * 128 + ((kg ^ lm) << 3)];
            #pragma unroll
            for (int ii = 0; ii < 4; ii++)
                #pragma unroll
                for (int jj = 0; jj < 4; jj++) {
                    if (MODE == 0)
                        acc[ii][jj] = __builtin_amdgcn_mfma_f32_16x16x32_bf16(bw[jj], af[ii], acc[ii][jj], 0,0,0);
                    else
                        acc[ii][jj] = __builtin_amdgcn_mfma_f32_16x16x32_bf16(af[ii], bw[jj], acc[ii][jj], 0,0,0);
                }
        }
        __syncthreads();
    }

    if (MODE == 0) {
        #pragma unroll
        for (int ii = 0; ii < 4; ii++) {
            int n = n0 + wn + ii * 16 + lm;
            #pragma unroll
            for (int jj = 0; jj < 4; jj++) {
                int mb = m0 + wm + jj * 16 + lg * 4;
                union { unsigned short us[4]; uint2 v; } pk;
                #pragma unroll
                for (int r = 0; r < 4; r++) pk.us[r] = f2bf(acc[ii][jj][r] + bias[mb + r]);
                *(uint2*)&Y16[((size_t)b * NPIX + n) * 256 + mb] = pk.v;
            }
        }
    } else {
        #pragma unroll
        for (int ii = 0; ii < 4; ii++) {
            int nb = n0 + wn + ii * 16 + lg * 4;
            #pragma unroll
            for (int jj = 0; jj < 4; jj++) {
                int m = m0 + wm + jj * 16 + lm;
                *(f32x4*)&Yf[((size_t)b * COUT + m) * NPIX + nb] = acc[ii][jj];
            }
        }
    }
}

// ---------------- fused KV-projection + MFMA attention ----------------
// grid (8, 256, 4) = (g, q, b); 320 threads = 5 waves, wave w owns d in [16w,16w+16)
// Phase 1 (per block): produce K[264s][32e] and V[32ch][264s] in LDS from corrT q-tile
//   (global, L3-served) x W_kv rows (L1-hot). mfma(Wk,ct) -> 4 consecutive e per lane
//   -> one ds_write_b64 into swizzled K layout; mfma(ct,Wv) -> 4 consecutive s per lane
//   -> one b64 into swizzled V layout. Bit-identical values to the old KV GEMM.
// Phase 2: identical to previous round (QK^T, bias, softmax, in-reg P transpose, PV).
// LDS: K at [0,17408) = [272 s][32 e]; V at [17408,35840) = [9 kk][32 ch][32 s].
// Swizzle: 16B-slot sl within each 256B macro-row stored at sl ^ (mr&15) (region-relative mr).
__global__ __launch_bounds__(320, 3) void attn_kernel(
    const unsigned short* __restrict__ corrT, // [b][NPAD][128]
    const unsigned short* __restrict__ wkv,   // [512][128] bf16: rows 0..255 Wk, 256..511 Wv
    const float* __restrict__ bkv,            // [512] fp32 bias: K then V
    const unsigned short* __restrict__ qpT,   // [b][NPIX][256]
    const float* __restrict__ bias272,        // [b][272] additive mask bias
    unsigned short* __restrict__ attT)        // [b][NPIX][256]
{
    int g = blockIdx.x, q = blockIdx.y, b = blockIdx.z;
    int t = threadIdx.x;
    int w = t >> 6, lane = t & 63;
    int lm = lane & 15, lg = lane >> 4;

    __shared__ __align__(16) unsigned short sbuf[17920];   // 35840 B: K then V
    const int VB = 8704;                                    // V base in shorts

    // Q frag (B operand: lane holds Q[d=16w+lm][e=g*32+lg*8+j]); clamp + zero d>=65
    int d = w * 16 + lm;
    int dc = d < 64 ? d : 64;
    bf16x8 qa = *(const bf16x8*)&qpT[((size_t)b * NPIX + q * 65 + dc) * 256 + g * 32 + lg * 8];
    if (d >= TD) { bf16x8 z = {}; qa = z; }

    // ---- phase 1: in-block K/V projection ----
    bf16x8 wkf[2][4], wvf[2][4];
    #pragma unroll
    for (int et = 0; et < 2; et++)
        #pragma unroll
        for (int ks = 0; ks < 4; ks++) {
            wkf[et][ks] = *(const bf16x8*)&wkv[(size_t)(g * 32 + et * 16 + lm) * 128 + ks * 32 + lg * 8];
            wvf[et][ks] = *(const bf16x8*)&wkv[(size_t)(256 + g * 32 + et * 16 + lm) * 128 + ks * 32 + lg * 8];
        }
    float bk_[2][4], bv_[2];
    #pragma unroll
    for (int et = 0; et < 2; et++) {
        #pragma unroll
        for (int r = 0; r < 4; r++) bk_[et][r] = bkv[g * 32 + et * 16 + lg * 4 + r];
        bv_[et] = bkv[256 + g * 32 + et * 16 + lm];
    }

    const unsigned short* cbase = corrT + ((size_t)b * NPAD + (size_t)q * 264) * 128;
    f32x4 zero4 = {0.f, 0.f, 0.f, 0.f};

    for (int st = w; st < 17; st += 5) {
        int srow = st * 16 + lm; if (srow > 263) srow = 263;   // pad rows are zeroed
        bf16x8 ct[4];
        #pragma unroll
        for (int ks = 0; ks < 4; ks++)
            ct[ks] = *(const bf16x8*)&cbase[(size_t)srow * 128 + ks * 32 + lg * 8];
        f32x4 ak0 = zero4, ak1 = zero4, av0 = zero4, av1 = zero4;
        #pragma unroll
        for (int ks = 0; ks < 4; ks++) {
            ak0 = __builtin_amdgcn_mfma_f32_16x16x32_bf16(wkf[0][ks], ct[ks], ak0, 0, 0, 0);
            ak1 = __builtin_amdgcn_mfma_f32_16x16x32_bf16(wkf[1][ks], ct[ks], ak1, 0, 0, 0);
            av0 = __builtin_amdgcn_mfma_f32_16x16x32_bf16(ct[ks], wvf[0][ks], av0, 0, 0, 0);
            av1 = __builtin_amdgcn_mfma_f32_16x16x32_bf16(ct[ks], wvf[1][ks], av1, 0, 0, 0);
        }
        // K writes: lane holds K[e=et*16+lg*4+r][s=st*16+lm]
        {
            int s = st * 16 + lm;
            #pragma unroll
            for (int et = 0; et < 2; et++) {
                unsigned u = (unsigned)(s * 64 + et * 32 + lg * 8);
                unsigned mr = u >> 8, sl = (u >> 4) & 15;
                unsigned us = (u & ~0xF0u) | ((sl ^ (mr & 15)) << 4);
                union { unsigned short e[4]; uint2 v; } pk;
                f32x4 a = et ? ak1 : ak0;
                #pragma unroll
                for (int r = 0; r < 4; r++) pk.e[r] = f2bf(a[r] + bk_[et][r]);
                *(uint2*)((char*)sbuf + us) = pk.v;
            }
        }
        // V writes: lane holds V[ch=et*16+lm][s=st*16+lg*4+r]
        {
            int s0 = st * 16 + lg * 4;
            unsigned vb_off = (unsigned)((s0 >> 5) * 2048 + (s0 & 31) * 2);
            #pragma unroll
            for (int et = 0; et < 2; et++) {
                int ch = et * 16 + lm;
                unsigned ov = vb_off + (unsigned)ch * 64u;
                unsigned mr = ov >> 8, sl = (ov >> 4) & 15;
                unsigned ovs = (ov & ~0xF0u) | ((sl ^ (mr & 15)) << 4);
                union { unsigned short e[4]; uint2 v; } pk;
                f32x4 a = et ? av1 : av0;
                #pragma unroll
                for (int r = 0; r < 4; r++) pk.e[r] = f2bf(a[r] + bv_[et]);
                *(uint2*)((char*)sbuf + 17408 + ovs) = pk.v;
            }
        }
    }
    // zero-fill V window s in [272,288)
    if (t < 128) {
        int ch = t >> 2, j = t & 3;
        unsigned ov = 16384u + (unsigned)ch * 64u + 32u + (unsigned)j * 8u;
        unsigned mr = ov >> 8, sl = (ov >> 4) & 15;
        unsigned ovs = (ov & ~0xF0u) | ((sl ^ (mr & 15)) << 4);
        uint2 z2; z2.x = 0u; z2.y = 0u;
        *(uint2*)((char*)sbuf + 17408 + ovs) = z2;
    }
    __syncthreads();

    // ---- phase 2: QK^T from LDS: c[tt] holds S^T[s=16tt+4lg+r][d=lm] ----
    f32x4 c[17];
    int sl0 = ((lm & 3) << 2) | lg;
    #pragma unroll
    for (int tt = 0; tt < 17; tt++) {
        int mr = tt * 4 + (lm >> 2);
        bf16x8 kf = *(const bf16x8*)&sbuf[mr * 128 + ((sl0 ^ (mr & 15)) << 3)];
        c[tt] = __builtin_amdgcn_mfma_f32_16x16x32_bf16(kf, qa, zero4, 0, 0, 0);
    }

    // additive mask bias: one aligned float4 per tile
    const float* bp = bias272 + b * 272 + lg * 4;
    #pragma unroll
    for (int tt = 0; tt < 17; tt++) {
        f32x4 bf = *(const f32x4*)&bp[tt * 16];
        c[tt][0] += bf[0]; c[tt][1] += bf[1]; c[tt][2] += bf[2]; c[tt][3] += bf[3];
    }

    // softmax: row d=lm lane-local over regs; reduce across lg via 2 shfls
    f32x4 mv = c[0];
    #pragma unroll
    for (int tt = 1; tt < 17; tt++) {
        mv[0] = fmaxf(mv[0], c[tt][0]); mv[1] = fmaxf(mv[1], c[tt][1]);
        mv[2] = fmaxf(mv[2], c[tt][2]); mv[3] = fmaxf(mv[3], c[tt][3]);
    }
    float mx = fmaxf(fmaxf(mv[0], mv[1]), fmaxf(mv[2], mv[3]));
    mx = fmaxf(mx, __shfl_xor(mx, 16));
    mx = fmaxf(mx, __shfl_xor(mx, 32));
    float sm = 0.f;
    #pragma unroll
    for (int tt = 0; tt < 17; tt++) {
        #pragma unroll
        for (int r = 0; r < 4; r++) { float e_ = __expf(c[tt][r] - mx); c[tt][r] = e_; sm += e_; }
    }
    sm += __shfl_xor(sm, 16);
    sm += __shfl_xor(sm, 32);
    float inv = 1.0f / sm;   // uniform across lg for fixed lm; applied at epilogue

    // pack P (unnormalized) to bf16 pairs
    unsigned plo[17], phi[17];
    #pragma unroll
    for (int tt = 0; tt < 17; tt++) {
        asm("v_cvt_pk_bf16_f32 %0, %1, %2" : "=v"(plo[tt]) : "v"(c[tt][0]), "v"(c[tt][1]));
        asm("v_cvt_pk_bf16_f32 %0, %1, %2" : "=v"(phi[tt]) : "v"(c[tt][2]), "v"(c[tt][3]));
    }

    // PV: in-register transpose (permlane32_swap + shfl_xor16) + V from LDS
    bool lgEven = (lane & 16) == 0;
    f32x4 o0 = zero4, o1 = zero4;
    #pragma unroll
    for (int kk = 0; kk < 9; kk++) {
        unsigned A = plo[2 * kk];
        unsigned C = phi[2 * kk];
        unsigned B = (2 * kk + 1 < 17) ? plo[2 * kk + 1] : 0u;
        unsigned D = (2 * kk + 1 < 17) ? phi[2 * kk + 1] : 0u;
        asm("v_permlane32_swap_b32 %0, %1" : "+v"(A), "+v"(B));
        asm("v_permlane32_swap_b32 %0, %1" : "+v"(C), "+v"(D));
        unsigned Ax = __shfl_xor(A, 16), Bx = __shfl_xor(B, 16);
        unsigned Cx = __shfl_xor(C, 16), Dx = __shfl_xor(D, 16);
        union { unsigned u[4]; bf16x8 v; } pa;
        pa.u[0] = lgEven ? A  : Bx;
        pa.u[1] = lgEven ? C  : Dx;
        pa.u[2] = lgEven ? Ax : B;
        pa.u[3] = lgEven ? Cx : D;
        int mr0 = kk * 8 + (lm >> 2), mr1 = mr0 + 4;
        bf16x8 v0 = *(const bf16x8*)&sbuf[VB + mr0 * 128 + ((sl0 ^ (mr0 & 15)) << 3)];
        bf16x8 v1 = *(const bf16x8*)&sbuf[VB + mr1 * 128 + ((sl0 ^ (mr1 & 15)) << 3)];
        o0 = __builtin_amdgcn_mfma_f32_16x16x32_bf16(pa.v, v0, o0, 0, 0, 0);
        o1 = __builtin_amdgcn_mfma_f32_16x16x32_bf16(pa.v, v1, o1, 0, 0, 0);
    }
    // epilogue: apply 1/sum (gather per-row inv) and store
    float invr[4];
    #pragma unroll
    for (int r = 0; r < 4; r++) invr[r] = __shfl(inv, lg * 4 + r);
    #pragma unroll
    for (int r = 0; r < 4; r++) {
        int dd = w * 16 + lg * 4 + r;
        if (dd < TD) {
            size_t nn = (size_t)b * NPIX + q * 65 + dd;
            attT[nn * 256 + g * 32 + lm]      = f2bf(o0[r] * invr[r]);
            attT[nn * 256 + g * 32 + 16 + lm] = f2bf(o1[r] * invr[r]);
        }
    }
}

// ---------------- stats over bf16 attT ----------------
__global__ void stats1_kernel(const unsigned short* __restrict__ attT, float* __restrict__ st) {
    int b = blockIdx.y;
    int t = threadIdx.x;
    int e8 = t & 31, g = e8 >> 3;
    int lane = t & 63;
    float s = 0.f, ss = 0.f;
    for (int r = blockIdx.x * 8 + (t >> 5); r < NPIX; r += gridDim.x * 8) {
        union { uint4 v; unsigned short us[8]; } u;
        u.v = *(const uint4*)&attT[((size_t)b * NPIX + r) * 256 + e8 * 8];
        #pragma unroll
        for (int j = 0; j < 8; j++) { float x = bf2f(u.us[j]); s += x; ss += x * x; }
    }
    s += __shfl_down(s, 32); ss += __shfl_down(ss, 32);
    s += __shfl_down(s, 4);  ss += __shfl_down(ss, 4);
    s += __shfl_down(s, 2);  ss += __shfl_down(ss, 2);
    s += __shfl_down(s, 1);  ss += __shfl_down(ss, 1);
    if (lane < 32 && (lane & 7) == 0) {
        atomicAdd(&st[(b * 4 + g) * 2],     s);
        atomicAdd(&st[(b * 4 + g) * 2 + 1], ss);
    }
}

// ---------------- stats over fp32 [b][C][NPIX] ----------------
__global__ void stats_kernel(const float* __restrict__ x, float* __restrict__ st, int Cg) {
    size_t len = (size_t)Cg * NPIX;
    size_t base = (size_t)blockIdx.y * len;
    const float4* x4 = reinterpret_cast<const float4*>(x + base);
    size_t len4 = len >> 2;
    float s = 0.f, ss = 0.f;
    for (size_t i = (size_t)blockIdx.x * blockDim.x + threadIdx.x; i < len4;
         i += (size_t)gridDim.x * blockDim.x) {
        float4 v = x4[i];
        s  += v.x + v.y + v.z + v.w;
        ss += v.x * v.x + v.y * v.y + v.z * v.z + v.w * v.w;
    }
    #pragma unroll
    for (int o = 32; o > 0; o >>= 1) { s += __shfl_down(s, o, 64); ss += __shfl_down(ss, o, 64); }
    __shared__ float red[4][2];
    int wid = threadIdx.x >> 6, lane = threadIdx.x & 63;
    if (lane == 0) { red[wid][0] = s; red[wid][1] = ss; }
    __syncthreads();
    if (threadIdx.x == 0) {
        float S  = red[0][0] + red[1][0] + red[2][0] + red[3][0];
        float SS = red[0][1] + red[1][1] + red[2][1] + red[3][1];
        atomicAdd(&st[blockIdx.y * 2],     S);
        atomicAdd(&st[blockIdx.y * 2 + 1], SS);
    }
}

// ---------------- z = relu(gn2(agg)) + relu(gn_sc(scr)) ----------------
__global__ void z_kernel(float* __restrict__ out, const float* __restrict__ scr,
                         const float* __restrict__ st2, const float* __restrict__ stsc,
                         const float* __restrict__ g2w, const float* __restrict__ g2b,
                         const float* __restrict__ gsw, const float* __restrict__ gsb)
{
    const float invcnt = 1.0f / (128.0f * NPIX);
    size_t total4 = (size_t)NB * COUT * (NPIX / 4);
    float4* o4 = reinterpret_cast<float4*>(out);
    const float4* s4 = reinterpret_cast<const float4*>(scr);
    for (size_t i = (size_t)blockIdx.x * blockDim.x + threadIdx.x; i < total4;
         i += (size_t)gridDim.x * blockDim.x) {
        size_t flat = i * 4;
        int c = (int)((flat / NPIX) % COUT);
        int b = (int)(flat / ((size_t)COUT * NPIX));
        int bg = b * 4 + (c >> 7);
        float2 p2 = gn_params(st2,  bg, invcnt);
        float2 ps = gn_params(stsc, bg, invcnt);
        float w2 = g2w[c] * p2.y, b2 = g2b[c] - p2.x * p2.y * g2w[c];
        float wsc = gsw[c] * ps.y, bsc = gsb[c] - ps.x * ps.y * gsw[c];
        float4 a = o4[i], r = s4[i], z;
        z.x = fmaxf(a.x * w2 + b2, 0.f) + fmaxf(r.x * wsc + bsc, 0.f);
        z.y = fmaxf(a.y * w2 + b2, 0.f) + fmaxf(r.y * wsc + bsc, 0.f);
        z.z = fmaxf(a.z * w2 + b2, 0.f) + fmaxf(r.z * wsc + bsc, 0.f);
        z.w = fmaxf(a.w * w2 + b2, 0.f) + fmaxf(r.w * wsc + bsc, 0.f);
        o4[i] = z;
    }
}

// ---------------- final gn_out ----------------
__global__ void norm_kernel(float* __restrict__ out, const float* __restrict__ st3,
                            const float* __restrict__ gw, const float* __restrict__ gb)
{
    const float invcnt = 1.0f / (128.0f * NPIX);
    size_t total4 = (size_t)NB * COUT * (NPIX / 4);
    float4* o4 = reinterpret_cast<float4*>(out);
    for (size_t i = (size_t)blockIdx.x * blockDim.x + threadIdx.x; i < total4;
         i += (size_t)gridDim.x * blockDim.x) {
        size_t flat = i * 4;
        int c = (int)((flat / NPIX) % COUT);
        int b = (int)(flat / ((size_t)COUT * NPIX));
        int bg = b * 4 + (c >> 7);
        float2 p = gn_params(st3, bg, invcnt);
        float w_ = gw[c] * p.y, b_ = gb[c] - p.x * p.y * gw[c];
        float4 a = o4[i], z;
        z.x = a.x * w_ + b_; z.y = a.y * w_ + b_; z.z = a.z * w_ + b_; z.w = a.w * w_ + b_;
        o4[i] = z;
    }
}

extern "C" void kernel_launch(void* const* d_in, const int* in_sizes, int n_in,
                              void* d_out, int out_size, void* d_ws, size_t ws_size,
                              hipStream_t stream) {
    (void)in_sizes; (void)n_in; (void)out_size; (void)ws_size;
    const float* corr     = (const float*)d_in[0];
    const int*   smask    = (const int*)  d_in[1];
    const float* W_sc     = (const float*)d_in[2];
    const float* gn_sc_w  = (const float*)d_in[3];
    const float* gn_sc_b  = (const float*)d_in[4];
    const float* W_qkv    = (const float*)d_in[5];
    const float* b_qkv    = (const float*)d_in[6];
    const float* gn1_w    = (const float*)d_in[7];
    const float* gn1_b    = (const float*)d_in[8];
    const float* W_agg    = (const float*)d_in[9];
    const float* gn2_w    = (const float*)d_in[10];
    const float* gn2_b    = (const float*)d_in[11];
    const float* gn_out_w = (const float*)d_in[12];
    const float* gn_out_b = (const float*)d_in[13];
    float* out = (float*)d_out;

    unsigned short* ws = (unsigned short*)d_ws;
    unsigned short* corrT  = ws;                           // 34,603,008 sh
    unsigned short* kbuf   = corrT  + (size_t)34603008;    // (dead space, kept for layout)
    unsigned short* vbuf   = kbuf   + (size_t)69206016;    // (dead space, kept for layout)
    unsigned short* corrpT = vbuf   + (size_t)69206016;    //  8,519,680 sh
    unsigned short* qpT    = corrpT + (size_t)8519680;     // 17,039,360 sh
    unsigned short* attT   = qpT    + (size_t)17039360;    // 17,039,360 sh
    unsigned short* wbuf   = attT   + (size_t)17039360;    //    294,912 sh
    float* bias  = (float*)(wbuf + (size_t)294912);        // 1,088 f  ([b][272])
    float* stats = bias + 1088;                            // 128 f
    float* scr   = (float*)d_ws;   // aliases corrT+kbuf head (dead by SC gemm)
    float* st_sc = stats, *st1 = stats + 32, *st2 = stats + 64, *st3 = stats + 96;
    (void)kbuf; (void)vbuf;

    const float inv1 = 1.0f / (64.0f * (float)NPIX);

    hipMemsetAsync(stats, 0, 128 * sizeof(float), stream);
    wprep_kernel<<<dim3(1152), dim3(256), 0, stream>>>(W_qkv, W_sc, W_agg, wbuf);
    mask_kernel<<<dim3(NB), dim3(320), 0, stream>>>(smask, bias);
    tpool_kernel<<<dim3(TQ, 2, NB), dim3(256), 0, stream>>>(corr, corrT, corrpT);
    // Q projection: qpT[b][n][256] = Wq x corrpT + bq
    mgemm_kernel<0,128><<<dim3(130, 2, NB), dim3(256), 0, stream>>>(
        corrpT, wbuf, NPIX, nullptr, qpT, b_qkv,
        nullptr, nullptr, nullptr, 0.f);
    // fused KV projection + attention (KV GEMM dispatch eliminated)
    attn_kernel<<<dim3(8, TQ, NB), dim3(320), 0, stream>>>(
        corrT, wbuf + 32768, b_qkv + 256, qpT, bias, attT);
    stats1_kernel<<<dim3(208, NB), dim3(256), 0, stream>>>(attT, st1);
    // agg conv with fused gn1+relu on input
    mgemm_kernel<3,256><<<dim3(130, 4, NB), dim3(256), 0, stream>>>(
        attT, wbuf + 163840, NPIX, out, nullptr, nullptr,
        st1, gn1_w, gn1_b, inv1);
    stats_kernel<<<dim3(64, 16), dim3(256), 0, stream>>>(out, st2, 128);
    // residual conv: scr = W_sc x corrpT
    mgemm_kernel<2,128><<<dim3(130, 4, NB), dim3(256), 0, stream>>>(
        corrpT, wbuf + 98304, NPIX, scr, nullptr, nullptr,
        nullptr, nullptr, nullptr, 0.f);
    stats_kernel<<<dim3(64, 16), dim3(256), 0, stream>>>(scr, st_sc, 128);
    z_kernel<<<dim3(4096), dim3(256), 0, stream>>>(out, scr, st2, st_sc, gn2_w, gn2_b, gn_sc_w, gn_sc_b);
    stats_kernel<<<dim3(64, 16), dim3(256), 0, stream>>>(out, st3, 128);
    norm_kernel<<<dim3(4096), dim3(256), 0, stream>>>(out, st3, gn_out_w, gn_out_b);
}